// Round 12
// baseline (1775.691 us; speedup 1.0000x reference)
//
#include <hip/hip_runtime.h>
#include <math.h>

#define NN 20000
#define NE 200000

typedef __attribute__((ext_vector_type(8))) short bf16x8;
typedef __attribute__((ext_vector_type(4))) float f32x4;

__device__ __forceinline__ unsigned short f2bf(float x) {
  union { float f; unsigned u; } c; c.f = x;
  unsigned r = c.u + 0x7FFF + ((c.u >> 16) & 1);
  return (unsigned short)(r >> 16);
}
__device__ __forceinline__ float bf2f(unsigned short u) {
  union { unsigned u; float f; } c; c.u = ((unsigned)u) << 16;
  return c.f;
}

// ---------------------------------------------------------------------------
// Encoder: out = relu(LN(in @ W + b))   in: [rows, D], W: [D,96]
// ---------------------------------------------------------------------------
__global__ __launch_bounds__(128) void encode_kernel(
    const float* __restrict__ in, int D,
    const float* __restrict__ W, const float* __restrict__ b,
    const float* __restrict__ g, const float* __restrict__ beta,
    float* __restrict__ out, unsigned short* __restrict__ outb) {
  int row = blockIdx.x;
  int t = threadIdx.x;
  __shared__ float vin[8];
  __shared__ float part[2][2];
  __shared__ float red[2];
  if (t < D) vin[t] = in[row * D + t];
  __syncthreads();
  float v = 0.f;
  if (t < 96) {
    v = b[t];
    for (int k = 0; k < D; k++) v += vin[k] * W[k * 96 + t];
  }
  float ps = (t < 96) ? v : 0.f;
  float ps2 = (t < 96) ? v * v : 0.f;
#pragma unroll
  for (int off = 32; off > 0; off >>= 1) {
    ps += __shfl_down(ps, off);
    ps2 += __shfl_down(ps2, off);
  }
  if ((t & 63) == 0) { part[t >> 6][0] = ps; part[t >> 6][1] = ps2; }
  __syncthreads();
  if (t == 0) {
    float s = part[0][0] + part[1][0];
    float s2 = part[0][1] + part[1][1];
    float mu = s / 96.f;
    float var = s2 / 96.f - mu * mu;
    red[0] = mu; red[1] = rsqrtf(var + 1e-5f);
  }
  __syncthreads();
  if (t < 96) {
    float y = (v - red[0]) * red[1] * g[t] + beta[t];
    y = fmaxf(y, 0.f);
    if (out)  out[(size_t)row * 96 + t] = y;
    if (outb) outb[(size_t)row * 96 + t] = f2bf(y);
  }
}

// ---------------------------------------------------------------------------
// Weight prep
// ---------------------------------------------------------------------------
__global__ void convW_kernel(const float* __restrict__ We,
                             unsigned short* __restrict__ WeTb,
                             const float* __restrict__ Wl,
                             unsigned short* __restrict__ WlTb,
                             const float* __restrict__ Wr,
                             unsigned short* __restrict__ WrTb,
                             const float* __restrict__ p1w,
                             unsigned short* __restrict__ p1wT,
                             const float* __restrict__ p2w,
                             unsigned short* __restrict__ p2wT) {
  int idx = blockIdx.x * 256 + threadIdx.x;
  if (idx < 3 * 576 * 96) {
    int l = idx / (576 * 96);
    int rem = idx % (576 * 96);
    int n = rem / 96, k = rem % 96;
    size_t sidx = (size_t)l * 96 * 576 + (size_t)k * 576 + n;
    WeTb[idx] = f2bf(We[sidx]);
    WlTb[idx] = f2bf(Wl[sidx]);
    WrTb[idx] = f2bf(Wr[sidx]);
  }
  if (idx < 128 * 288) {
    int n = idx / 288, k = idx % 288;
    p1wT[idx] = f2bf(p1w[(size_t)k * 128 + n]);
  }
  if (idx < 64 * 128) {
    int n = idx / 128, k = idx % 128;
    p2wT[idx] = f2bf(p2w[(size_t)k * 64 + n]);
  }
}

// ---------------------------------------------------------------------------
// CSR build by dst
// ---------------------------------------------------------------------------
__global__ void hist_kernel(const int* __restrict__ dst, int* __restrict__ deg) {
  int e = blockIdx.x * blockDim.x + threadIdx.x;
  if (e < NE) atomicAdd(&deg[dst[e]], 1);
}

__global__ __launch_bounds__(1024) void scan_kernel(
    const int* __restrict__ deg, int* __restrict__ rowptr, int* __restrict__ cursor) {
  __shared__ int buf[1024];
  __shared__ int carry_s;
  int t = threadIdx.x;
  if (t == 0) carry_s = 0;
  __syncthreads();
  for (int base = 0; base < NN; base += 1024) {
    int i = base + t;
    int v = (i < NN) ? deg[i] : 0;
    buf[t] = v;
    __syncthreads();
    for (int off = 1; off < 1024; off <<= 1) {
      int add = (t >= off) ? buf[t - off] : 0;
      __syncthreads();
      buf[t] += add;
      __syncthreads();
    }
    int carry = carry_s;
    int excl = carry + buf[t] - v;
    if (i < NN) { rowptr[i] = excl; cursor[i] = excl; }
    __syncthreads();
    if (t == 1023) carry_s = carry + buf[1023];
    __syncthreads();
  }
  if (t == 0) rowptr[NN] = NE;
}

__global__ void scatter_kernel(const int* __restrict__ src,
                               const int* __restrict__ dst,
                               int* __restrict__ cursor, int* __restrict__ eidx,
                               int* __restrict__ srcp) {
  int e = blockIdx.x * blockDim.x + threadIdx.x;
  if (e < NE) {
    int d = dst[e];
    int p = atomicAdd(&cursor[d], 1);
    eidx[p] = e;
    srcp[p] = src[e];
  }
}

// ---------------------------------------------------------------------------
// xlxr via MFMA (verified R8)
// ---------------------------------------------------------------------------
__global__ __launch_bounds__(256) void xlxr_mfma_kernel(
    const unsigned short* __restrict__ Xb,    // [NN][96]
    const unsigned short* __restrict__ WlTb,  // [576][96]
    const float* __restrict__ bl,
    const unsigned short* __restrict__ WrTb,  // [576][96]
    const float* __restrict__ br,
    unsigned short* __restrict__ xlb, unsigned short* __restrict__ xrb) {
  int t = threadIdx.x;
  int wave = t >> 6, lane = t & 63;
  int l15 = lane & 15, quad = lane >> 4;
  int node = blockIdx.x * 64 + wave * 16 + l15;
  int nclamp = (node < NN) ? node : (NN - 1);
  bool valid = node < NN;
  const unsigned short* brow = &Xb[(size_t)nclamp * 96 + quad * 8];
  bf16x8 b0 = *(const bf16x8*)&brow[0];
  bf16x8 b1 = *(const bf16x8*)&brow[32];
  bf16x8 b2 = *(const bf16x8*)&brow[64];
#pragma unroll
  for (int mt = 0; mt < 36; mt++) {
    int wc = mt * 16 + l15;
    const unsigned short* aL = &WlTb[(size_t)wc * 96 + quad * 8];
    f32x4 accL = {0.f, 0.f, 0.f, 0.f};
    accL = __builtin_amdgcn_mfma_f32_16x16x32_bf16(*(const bf16x8*)&aL[0], b0, accL, 0, 0, 0);
    accL = __builtin_amdgcn_mfma_f32_16x16x32_bf16(*(const bf16x8*)&aL[32], b1, accL, 0, 0, 0);
    accL = __builtin_amdgcn_mfma_f32_16x16x32_bf16(*(const bf16x8*)&aL[64], b2, accL, 0, 0, 0);
    const unsigned short* aR = &WrTb[(size_t)wc * 96 + quad * 8];
    f32x4 accR = {0.f, 0.f, 0.f, 0.f};
    accR = __builtin_amdgcn_mfma_f32_16x16x32_bf16(*(const bf16x8*)&aR[0], b0, accR, 0, 0, 0);
    accR = __builtin_amdgcn_mfma_f32_16x16x32_bf16(*(const bf16x8*)&aR[32], b1, accR, 0, 0, 0);
    accR = __builtin_amdgcn_mfma_f32_16x16x32_bf16(*(const bf16x8*)&aR[64], b2, accR, 0, 0, 0);
    if (valid) {
      int c0 = mt * 16 + quad * 4;
      float4 bbL = *(const float4*)&bl[c0];
      float4 bbR = *(const float4*)&br[c0];
      ushort4 pL, pR;
      pL.x = f2bf(accL[0] + bbL.x); pL.y = f2bf(accL[1] + bbL.y);
      pL.z = f2bf(accL[2] + bbL.z); pL.w = f2bf(accL[3] + bbL.w);
      pR.x = f2bf(accR[0] + bbR.x); pR.y = f2bf(accR[1] + bbR.y);
      pR.z = f2bf(accR[2] + bbR.z); pR.w = f2bf(accR[3] + bbR.w);
      *(ushort4*)&xlb[(size_t)node * 576 + c0] = pL;
      *(ushort4*)&xrb[(size_t)node * 576 + c0] = pR;
    }
  }
}

// ---------------------------------------------------------------------------
// Fused GAT layer: one block per dst node (192 thr = 3 waves x 2 heads).
// Per 16-edge chunk: stage xl[src] rows to LDS once; ee via MFMA (R3 layout);
// logits = dot(attw, leaky(ee+xl+xr)) with xl from LDS, xr one row (dst);
// online softmax (R5); weighted sum re-reads the SAME LDS xl rows.
// Epilogue: head-mean + cbias + elu + LN + residual -> x, xb.
// ---------------------------------------------------------------------------
__global__ __launch_bounds__(192) void gat_fused_kernel(
    const unsigned short* __restrict__ EMBb,   // [NE][96]
    const unsigned short* __restrict__ WeTb,   // [576][96]
    const float* __restrict__ attw,            // [576]
    const unsigned short* __restrict__ XLb,    // [NN][576]
    const unsigned short* __restrict__ XRb,    // [NN][576]
    const int* __restrict__ rowptr, const int* __restrict__ srcp,
    const int* __restrict__ eidx,
    float* __restrict__ x, unsigned short* __restrict__ xb,
    const float* __restrict__ cbias, const float* __restrict__ lng,
    const float* __restrict__ lnb, int do_elu) {
  __shared__ __align__(16) unsigned short xls[16][584];
  __shared__ __align__(16) unsigned short xrs[584];
  __shared__ float lg[16][6];
  __shared__ float alf[16][6];
  __shared__ float m6[6], s6[6], f6[6];
  __shared__ float scratch[576];
  __shared__ float fin[96];
  __shared__ float part2[2][2];
  __shared__ float red[2];

  int n = blockIdx.x;
  int t = threadIdx.x;
  int wave = t >> 6, lane = t & 63;
  int l15 = lane & 15, quad = lane >> 4;
  int r0 = rowptr[n];
  int d = rowptr[n + 1] - r0;

  // stage xr row of dst node n (once)
  for (int idx = t; idx < 72; idx += 192)
    *(bf16x8*)&xrs[idx * 8] = *(const bf16x8*)&XRb[(size_t)n * 576 + idx * 8];
  if (t < 6) { m6[t] = -1e30f; s6[t] = 0.f; }

  int hcol = t / 32;   // head owning cols 3t..3t+2
  float acc0 = 0.f, acc1 = 0.f, acc2 = 0.f;

  for (int cs = 0; cs < d; cs += 16) {
    int cnt = min(16, d - cs);
    __syncthreads();   // xls reuse + init/xrs visibility
    // stage xl rows for this chunk
    for (int idx = t; idx < cnt * 72; idx += 192) {
      int j = idx / 72, c = idx % 72;
      *(bf16x8*)&xls[j][c * 8] =
          *(const bf16x8*)&XLb[(size_t)srcp[r0 + cs + j] * 576 + c * 8];
    }
    // A fragments: lane l15 = edge j (clamped)
    int j = (l15 < cnt) ? l15 : (cnt - 1);
    int erow = eidx[r0 + cs + j];
    const unsigned short* ar = &EMBb[(size_t)erow * 96 + quad * 8];
    bf16x8 a0 = *(const bf16x8*)&ar[0];
    bf16x8 a1 = *(const bf16x8*)&ar[32];
    bf16x8 a2 = *(const bf16x8*)&ar[64];
    __syncthreads();   // xls ready
    // MFMA + combine: wave w -> heads 2w, 2w+1
#pragma unroll
    for (int hl = 0; hl < 2; hl++) {
      int h = 2 * wave + hl;
      float part[4] = {0.f, 0.f, 0.f, 0.f};
#pragma unroll
      for (int nt6 = 0; nt6 < 6; nt6++) {
        int col = (12 * wave + 6 * hl + nt6) * 16 + l15;
        const unsigned short* brow = &WeTb[(size_t)col * 96 + quad * 8];
        bf16x8 b0 = *(const bf16x8*)&brow[0];
        bf16x8 b1 = *(const bf16x8*)&brow[32];
        bf16x8 b2 = *(const bf16x8*)&brow[64];
        f32x4 acc = {0.f, 0.f, 0.f, 0.f};
        acc = __builtin_amdgcn_mfma_f32_16x16x32_bf16(a0, b0, acc, 0, 0, 0);
        acc = __builtin_amdgcn_mfma_f32_16x16x32_bf16(a1, b1, acc, 0, 0, 0);
        acc = __builtin_amdgcn_mfma_f32_16x16x32_bf16(a2, b2, acc, 0, 0, 0);
        float aw = attw[col];
        float xrv = bf2f(xrs[col]);
#pragma unroll
        for (int r = 0; r < 4; r++) {
          int e = quad * 4 + r;
          float v = acc[r] + bf2f(xls[e][col]) + xrv;
          v = (v > 0.f) ? v : 0.2f * v;
          part[r] += v * aw;
        }
      }
#pragma unroll
      for (int r = 0; r < 4; r++) {
        float p = part[r];
        p += __shfl_xor(p, 1);
        p += __shfl_xor(p, 2);
        p += __shfl_xor(p, 4);
        p += __shfl_xor(p, 8);
        int e = quad * 4 + r;
        if (l15 == 0 && e < cnt) lg[e][h] = p;
      }
    }
    __syncthreads();   // lg ready
    // online softmax: 96 threads, (j2, h2) pairs, 16-lane shfl groups
    bool sact = (wave == 0) || (wave == 1 && lane < 32);
    if (sact) {
      int j2 = lane & 15;
      int h2 = (wave == 0) ? (lane >> 4) : 4 + (lane >> 4);
      float lv = (j2 < cnt) ? lg[j2][h2] : -1e30f;
      float cm = lv;
      cm = fmaxf(cm, __shfl_xor(cm, 1));
      cm = fmaxf(cm, __shfl_xor(cm, 2));
      cm = fmaxf(cm, __shfl_xor(cm, 4));
      cm = fmaxf(cm, __shfl_xor(cm, 8));
      float mold = m6[h2];
      float newm = fmaxf(mold, cm);
      float wv = (j2 < cnt) ? expf(lv - newm) : 0.f;
      alf[j2][h2] = wv;
      float ss = wv;
      ss += __shfl_xor(ss, 1);
      ss += __shfl_xor(ss, 2);
      ss += __shfl_xor(ss, 4);
      ss += __shfl_xor(ss, 8);
      float f = expf(mold - newm);
      if (j2 == 0) { s6[h2] = s6[h2] * f + ss; m6[h2] = newm; f6[h2] = f; }
    }
    __syncthreads();   // alf, f6 ready
    // weighted accumulate from LDS-staged xl rows
    float fr = f6[hcol];
    acc0 *= fr; acc1 *= fr; acc2 *= fr;
    int c0 = 3 * t;
    for (int jj = 0; jj < cnt; jj++) {
      float a = alf[jj][hcol];
      acc0 += a * bf2f(xls[jj][c0 + 0]);
      acc1 += a * bf2f(xls[jj][c0 + 1]);
      acc2 += a * bf2f(xls[jj][c0 + 2]);
    }
  }
  __syncthreads();   // s6 visible (also covers d==0 init)
  float inv = 1.f / (s6[hcol] + 1e-16f);
  scratch[3 * t + 0] = acc0 * inv;
  scratch[3 * t + 1] = acc1 * inv;
  scratch[3 * t + 2] = acc2 * inv;
  __syncthreads();
  float fv = 0.f;
  if (t < 96) {
    float s = 0.f;
    for (int hh = 0; hh < 6; hh++) s += scratch[hh * 96 + t];
    s = s * (1.f / 6.f) + cbias[t];
    if (do_elu) s = (s > 0.f) ? s : expm1f(s);
    fv = s;
    fin[t] = s;
  }
  if (wave < 2) {
    float ps = (t < 96) ? fv : 0.f;
    float ps2 = (t < 96) ? fv * fv : 0.f;
#pragma unroll
    for (int off = 32; off > 0; off >>= 1) {
      ps += __shfl_xor(ps, off);
      ps2 += __shfl_xor(ps2, off);
    }
    if (lane == 0) { part2[wave][0] = ps; part2[wave][1] = ps2; }
  }
  __syncthreads();
  if (t == 0) {
    float s = part2[0][0] + part2[1][0];
    float s2 = part2[0][1] + part2[1][1];
    float mu = s / 96.f;
    float var = s2 / 96.f - mu * mu;
    red[0] = mu; red[1] = rsqrtf(var + 1e-5f);
  }
  __syncthreads();
  if (t < 96) {
    float y = (fin[t] - red[0]) * red[1] * lng[t] + lnb[t];
    float nv = x[(size_t)n * 96 + t] + y;
    x[(size_t)n * 96 + t] = nv;
    xb[(size_t)n * 96 + t] = f2bf(nv);
  }
}

// ---------------------------------------------------------------------------
// Predictor via MFMA (verified in R4)
// ---------------------------------------------------------------------------
__global__ __launch_bounds__(256) void pred_mfma_kernel(
    const unsigned short* __restrict__ Xb,     // [NN][96]
    const unsigned short* __restrict__ EMBb,   // [NE][96]
    const int* __restrict__ src, const int* __restrict__ dst,
    const unsigned short* __restrict__ p1wT,   // [128][288]
    const float* __restrict__ p1b, const float* __restrict__ p1g,
    const float* __restrict__ p1be,
    const unsigned short* __restrict__ p2wT,   // [64][128]
    const float* __restrict__ p2b, const float* __restrict__ p2g,
    const float* __restrict__ p2be,
    const float* __restrict__ p3w, const float* __restrict__ p3b,
    float* __restrict__ out) {
  __shared__ unsigned short h1s[4][16][136];
  int t = threadIdx.x;
  int wave = t >> 6, lane = t & 63;
  int l15 = lane & 15, quad = lane >> 4;
  int ebase = blockIdx.x * 64 + wave * 16;
  int erow = ebase + l15;
  int sN = src[erow], dN = dst[erow];

  bf16x8 A[9];
  const unsigned short* xs = &Xb[(size_t)sN * 96 + quad * 8];
  const unsigned short* xd = &Xb[(size_t)dN * 96 + quad * 8];
  const unsigned short* em = &EMBb[(size_t)erow * 96 + quad * 8];
#pragma unroll
  for (int c = 0; c < 3; c++) {
    A[c]     = *(const bf16x8*)&xs[c * 32];
    A[c + 3] = *(const bf16x8*)&xd[c * 32];
    A[c + 6] = *(const bf16x8*)&em[c * 32];
  }

  f32x4 C1[8];
#pragma unroll
  for (int nt = 0; nt < 8; nt++) {
    f32x4 acc = {0.f, 0.f, 0.f, 0.f};
    const unsigned short* bp = &p1wT[(size_t)(nt * 16 + l15) * 288 + quad * 8];
#pragma unroll
    for (int c = 0; c < 9; c++) {
      bf16x8 B = *(const bf16x8*)&bp[c * 32];
      acc = __builtin_amdgcn_mfma_f32_16x16x32_bf16(A[c], B, acc, 0, 0, 0);
    }
    float bias = p1b[nt * 16 + l15];
    acc[0] += bias; acc[1] += bias; acc[2] += bias; acc[3] += bias;
    C1[nt] = acc;
  }

  float mu1[4], rs1[4];
#pragma unroll
  for (int r = 0; r < 4; r++) {
    float s = 0.f, s2 = 0.f;
#pragma unroll
    for (int nt = 0; nt < 8; nt++) { float v = C1[nt][r]; s += v; s2 += v * v; }
    s += __shfl_xor(s, 1);  s += __shfl_xor(s, 2);
    s += __shfl_xor(s, 4);  s += __shfl_xor(s, 8);
    s2 += __shfl_xor(s2, 1); s2 += __shfl_xor(s2, 2);
    s2 += __shfl_xor(s2, 4); s2 += __shfl_xor(s2, 8);
    float mu = s * (1.f / 128.f);
    float var = s2 * (1.f / 128.f) - mu * mu;
    mu1[r] = mu;
    rs1[r] = rsqrtf(var + 1e-5f);
  }
#pragma unroll
  for (int nt = 0; nt < 8; nt++) {
    float g = p1g[nt * 16 + l15], be = p1be[nt * 16 + l15];
#pragma unroll
    for (int r = 0; r < 4; r++) {
      float v = (C1[nt][r] - mu1[r]) * rs1[r] * g + be;
      v = fmaxf(v, 0.f);
      h1s[wave][quad * 4 + r][nt * 16 + l15] = f2bf(v);
    }
  }
  __syncthreads();

  f32x4 C2[4];
#pragma unroll
  for (int nt = 0; nt < 4; nt++) {
    f32x4 acc = {0.f, 0.f, 0.f, 0.f};
    const unsigned short* bp = &p2wT[(size_t)(nt * 16 + l15) * 128 + quad * 8];
#pragma unroll
    for (int c = 0; c < 4; c++) {
      bf16x8 Af = *(const bf16x8*)&h1s[wave][l15][c * 32 + quad * 8];
      bf16x8 B = *(const bf16x8*)&bp[c * 32];
      acc = __builtin_amdgcn_mfma_f32_16x16x32_bf16(Af, B, acc, 0, 0, 0);
    }
    float bias = p2b[nt * 16 + l15];
    acc[0] += bias; acc[1] += bias; acc[2] += bias; acc[3] += bias;
    C2[nt] = acc;
  }

  float mu2[4], rs2[4];
#pragma unroll
  for (int r = 0; r < 4; r++) {
    float s = 0.f, s2 = 0.f;
#pragma unroll
    for (int nt = 0; nt < 4; nt++) { float v = C2[nt][r]; s += v; s2 += v * v; }
    s += __shfl_xor(s, 1);  s += __shfl_xor(s, 2);
    s += __shfl_xor(s, 4);  s += __shfl_xor(s, 8);
    s2 += __shfl_xor(s2, 1); s2 += __shfl_xor(s2, 2);
    s2 += __shfl_xor(s2, 4); s2 += __shfl_xor(s2, 8);
    float mu = s * (1.f / 64.f);
    float var = s2 * (1.f / 64.f) - mu * mu;
    mu2[r] = mu;
    rs2[r] = rsqrtf(var + 1e-5f);
  }

  float partial[4] = {0.f, 0.f, 0.f, 0.f};
#pragma unroll
  for (int nt = 0; nt < 4; nt++) {
    float g = p2g[nt * 16 + l15], be = p2be[nt * 16 + l15];
    float pw = p3w[nt * 16 + l15];
#pragma unroll
    for (int r = 0; r < 4; r++) {
      float v = (C2[nt][r] - mu2[r]) * rs2[r] * g + be;
      v = fmaxf(v, 0.f);
      partial[r] += v * pw;
    }
  }
#pragma unroll
  for (int r = 0; r < 4; r++) {
    float p = partial[r];
    p += __shfl_xor(p, 1);
    p += __shfl_xor(p, 2);
    p += __shfl_xor(p, 4);
    p += __shfl_xor(p, 8);
    partial[r] = p;
  }
  if (l15 == 0) {
    float b3 = p3b[0];
#pragma unroll
    for (int r = 0; r < 4; r++)
      out[ebase + quad * 4 + r] = partial[r] + b3;
  }
}

// ---------------------------------------------------------------------------
static inline size_t alignup(size_t v) { return (v + 255) & ~(size_t)255; }

extern "C" void kernel_launch(void* const* d_in, const int* in_sizes, int n_in,
                              void* d_out, int out_size, void* d_ws, size_t ws_size,
                              hipStream_t stream) {
  const float* x_in      = (const float*)d_in[0];
  const float* edge_attr = (const float*)d_in[1];
  const int*   ei        = (const int*)d_in[2];
  const int* src = ei;
  const int* dst = ei + NE;
  const float* ne_w = (const float*)d_in[3];
  const float* ne_b = (const float*)d_in[4];
  const float* ne_g = (const float*)d_in[5];
  const float* ne_be = (const float*)d_in[6];
  const float* ee_w = (const float*)d_in[7];
  const float* ee_b = (const float*)d_in[8];
  const float* ee_g = (const float*)d_in[9];
  const float* ee_be = (const float*)d_in[10];
  const float* Wl = (const float*)d_in[11];
  const float* bl = (const float*)d_in[12];
  const float* Wr = (const float*)d_in[13];
  const float* br = (const float*)d_in[14];
  const float* We = (const float*)d_in[15];
  const float* attw = (const float*)d_in[16];
  const float* cbias = (const float*)d_in[17];
  const float* lng = (const float*)d_in[18];
  const float* lnb = (const float*)d_in[19];
  const float* p1w = (const float*)d_in[20];
  const float* p1b = (const float*)d_in[21];
  const float* p1g = (const float*)d_in[22];
  const float* p1be = (const float*)d_in[23];
  const float* p2w = (const float*)d_in[24];
  const float* p2b = (const float*)d_in[25];
  const float* p2g = (const float*)d_in[26];
  const float* p2be = (const float*)d_in[27];
  const float* p3w = (const float*)d_in[28];
  const float* p3b = (const float*)d_in[29];
  float* out = (float*)d_out;

  // workspace carve (aligned)
  char* w = (char*)d_ws;
  float* X    = (float*)w; w += alignup((size_t)NN * 96 * 4);
  unsigned short* EMBb = (unsigned short*)w; w += alignup((size_t)NE * 96 * 2);
  unsigned short* XLb  = (unsigned short*)w; w += alignup((size_t)NN * 576 * 2);
  unsigned short* XRb  = (unsigned short*)w; w += alignup((size_t)NN * 576 * 2);
  unsigned short* Xb   = (unsigned short*)w; w += alignup((size_t)NN * 96 * 2);
  unsigned short* WeTb = (unsigned short*)w; w += alignup((size_t)3 * 576 * 96 * 2);
  unsigned short* WlTb = (unsigned short*)w; w += alignup((size_t)3 * 576 * 96 * 2);
  unsigned short* WrTb = (unsigned short*)w; w += alignup((size_t)3 * 576 * 96 * 2);
  unsigned short* p1wT = (unsigned short*)w; w += alignup((size_t)128 * 288 * 2);
  unsigned short* p2wT = (unsigned short*)w; w += alignup((size_t)64 * 128 * 2);
  int* deg    = (int*)w; w += alignup((size_t)(NN + 1) * 4);
  int* rowptr = (int*)w; w += alignup((size_t)(NN + 1) * 4);
  int* cursor = (int*)w; w += alignup((size_t)NN * 4);
  int* eidx   = (int*)w; w += alignup((size_t)NE * 4);
  int* srcp   = (int*)w; w += alignup((size_t)NE * 4);

  // encoders + weight prep
  encode_kernel<<<NN, 128, 0, stream>>>(x_in, 4, ne_w, ne_b, ne_g, ne_be, X, Xb);
  encode_kernel<<<NE, 128, 0, stream>>>(edge_attr, 3, ee_w, ee_b, ee_g, ee_be,
                                        nullptr, EMBb);
  convW_kernel<<<(3 * 576 * 96 + 255) / 256, 256, 0, stream>>>(
      We, WeTb, Wl, WlTb, Wr, WrTb, p1w, p1wT, p2w, p2wT);

  // CSR by dst
  hipMemsetAsync(deg, 0, (size_t)(NN + 1) * 4, stream);
  hist_kernel<<<(NE + 255) / 256, 256, 0, stream>>>(dst, deg);
  scan_kernel<<<1, 1024, 0, stream>>>(deg, rowptr, cursor);
  scatter_kernel<<<(NE + 255) / 256, 256, 0, stream>>>(src, dst, cursor, eidx,
                                                       srcp);

  // 3 GATv2 layers (fused logits+softmax+aggregate per dst node)
  for (int i = 0; i < 3; i++) {
    const unsigned short* WlT_i = WlTb + (size_t)i * 576 * 96;
    const float* bl_i = bl + (size_t)i * 576;
    const unsigned short* WrT_i = WrTb + (size_t)i * 576 * 96;
    const float* br_i = br + (size_t)i * 576;
    const unsigned short* WeT_i = WeTb + (size_t)i * 576 * 96;
    const float* aw_i = attw + (size_t)i * 576;
    const float* cb_i = cbias + (size_t)i * 96;
    const float* lg_i = lng + (size_t)i * 96;
    const float* lb_i = lnb + (size_t)i * 96;
    xlxr_mfma_kernel<<<(NN + 63) / 64, 256, 0, stream>>>(Xb, WlT_i, bl_i,
                                                         WrT_i, br_i, XLb, XRb);
    gat_fused_kernel<<<NN, 192, 0, stream>>>(EMBb, WeT_i, aw_i, XLb, XRb,
                                             rowptr, srcp, eidx, X, Xb,
                                             cb_i, lg_i, lb_i, (i < 2) ? 1 : 0);
  }

  // predictor (MFMA)
  pred_mfma_kernel<<<NE / 64, 256, 0, stream>>>(Xb, EMBb, src, dst,
                                                p1wT, p1b, p1g, p1be,
                                                p2wT, p2b, p2g, p2be,
                                                p3w, p3b, out);
}

// Round 13
// 1197.866 us; speedup vs baseline: 1.4824x; 1.4824x over previous
//
#include <hip/hip_runtime.h>
#include <math.h>

#define NN 20000
#define NE 200000

typedef __attribute__((ext_vector_type(8))) short bf16x8;
typedef __attribute__((ext_vector_type(4))) float f32x4;

__device__ __forceinline__ unsigned short f2bf(float x) {
  union { float f; unsigned u; } c; c.f = x;
  unsigned r = c.u + 0x7FFF + ((c.u >> 16) & 1);
  return (unsigned short)(r >> 16);
}
__device__ __forceinline__ float bf2f(unsigned short u) {
  union { unsigned u; float f; } c; c.u = ((unsigned)u) << 16;
  return c.f;
}

// ---------------------------------------------------------------------------
// Encoder (4 rows/block): out = relu(LN(in @ W + b))   in: [rows, D], W: [D,96]
// 512 threads = 4 row-groups of 128 (2 waves each).
// ---------------------------------------------------------------------------
__global__ __launch_bounds__(512) void encode4_kernel(
    const float* __restrict__ in, int D,
    const float* __restrict__ W, const float* __restrict__ b,
    const float* __restrict__ g, const float* __restrict__ beta,
    float* __restrict__ out, unsigned short* __restrict__ outb) {
  int rg = threadIdx.x >> 7;
  int tt = threadIdx.x & 127;
  int row = blockIdx.x * 4 + rg;
  __shared__ float vin[4][8];
  __shared__ float part[4][2][2];
  __shared__ float red[4][2];
  if (tt < D) vin[rg][tt] = in[(size_t)row * D + tt];
  __syncthreads();
  float v = 0.f;
  if (tt < 96) {
    v = b[tt];
    for (int k = 0; k < D; k++) v += vin[rg][k] * W[k * 96 + tt];
  }
  float ps = (tt < 96) ? v : 0.f;
  float ps2 = (tt < 96) ? v * v : 0.f;
#pragma unroll
  for (int off = 32; off > 0; off >>= 1) {
    ps += __shfl_down(ps, off);
    ps2 += __shfl_down(ps2, off);
  }
  if ((tt & 63) == 0) { part[rg][tt >> 6][0] = ps; part[rg][tt >> 6][1] = ps2; }
  __syncthreads();
  if (tt == 0) {
    float s = part[rg][0][0] + part[rg][1][0];
    float s2 = part[rg][0][1] + part[rg][1][1];
    float mu = s / 96.f;
    float var = s2 / 96.f - mu * mu;
    red[rg][0] = mu; red[rg][1] = rsqrtf(var + 1e-5f);
  }
  __syncthreads();
  if (tt < 96) {
    float y = (v - red[rg][0]) * red[rg][1] * g[tt] + beta[tt];
    y = fmaxf(y, 0.f);
    if (out)  out[(size_t)row * 96 + tt] = y;
    if (outb) outb[(size_t)row * 96 + tt] = f2bf(y);
  }
}

// ---------------------------------------------------------------------------
// Weight prep
// ---------------------------------------------------------------------------
__global__ void convW_kernel(const float* __restrict__ We,
                             unsigned short* __restrict__ WeTb,
                             const float* __restrict__ Wl,
                             unsigned short* __restrict__ WlTb,
                             const float* __restrict__ Wr,
                             unsigned short* __restrict__ WrTb,
                             const float* __restrict__ p1w,
                             unsigned short* __restrict__ p1wT,
                             const float* __restrict__ p2w,
                             unsigned short* __restrict__ p2wT) {
  int idx = blockIdx.x * 256 + threadIdx.x;
  if (idx < 3 * 576 * 96) {
    int l = idx / (576 * 96);
    int rem = idx % (576 * 96);
    int n = rem / 96, k = rem % 96;
    size_t sidx = (size_t)l * 96 * 576 + (size_t)k * 576 + n;
    WeTb[idx] = f2bf(We[sidx]);
    WlTb[idx] = f2bf(Wl[sidx]);
    WrTb[idx] = f2bf(Wr[sidx]);
  }
  if (idx < 128 * 288) {
    int n = idx / 288, k = idx % 288;
    p1wT[idx] = f2bf(p1w[(size_t)k * 128 + n]);
  }
  if (idx < 64 * 128) {
    int n = idx / 128, k = idx % 128;
    p2wT[idx] = f2bf(p2w[(size_t)k * 64 + n]);
  }
}

// ---------------------------------------------------------------------------
// CSR build by dst
// ---------------------------------------------------------------------------
__global__ void hist_kernel(const int* __restrict__ dst, int* __restrict__ deg) {
  int e = blockIdx.x * blockDim.x + threadIdx.x;
  if (e < NE) atomicAdd(&deg[dst[e]], 1);
}

// fast scan: 20 nodes/thread serial prefix + wave shfl scan + 16-wave scan
__global__ __launch_bounds__(1024) void scan_kernel(
    const int* __restrict__ deg, int* __restrict__ rowptr, int* __restrict__ cursor) {
  __shared__ int wsum[16];
  int t = threadIdx.x;
  int base = t * 20;
  int loc[20];
  int s = 0;
#pragma unroll
  for (int j = 0; j < 20; j++) {
    int idx = base + j;
    int v = (idx < NN) ? deg[idx] : 0;
    loc[j] = s;
    s += v;
  }
  int lane = t & 63, wv = t >> 6;
  int inc = s;
#pragma unroll
  for (int off = 1; off < 64; off <<= 1) {
    int up = __shfl_up(inc, off);
    if (lane >= off) inc += up;
  }
  if (lane == 63) wsum[wv] = inc;
  __syncthreads();
  if (wv == 0) {
    int wval = (lane < 16) ? wsum[lane] : 0;
#pragma unroll
    for (int off = 1; off < 16; off <<= 1) {
      int up = __shfl_up(wval, off);
      if (lane >= off) wval += up;
    }
    if (lane < 16) wsum[lane] = wval;
  }
  __syncthreads();
  int wbase = (wv > 0) ? wsum[wv - 1] : 0;
  int excl = wbase + inc - s;
#pragma unroll
  for (int j = 0; j < 20; j++) {
    int idx = base + j;
    if (idx < NN) { rowptr[idx] = excl + loc[j]; cursor[idx] = excl + loc[j]; }
  }
  if (t == 0) rowptr[NN] = NE;
}

__global__ void scatter_kernel(const int* __restrict__ src,
                               const int* __restrict__ dst,
                               int* __restrict__ cursor, int* __restrict__ eidx,
                               int* __restrict__ srcp, int* __restrict__ dstp) {
  int e = blockIdx.x * blockDim.x + threadIdx.x;
  if (e < NE) {
    int d = dst[e];
    int p = atomicAdd(&cursor[d], 1);
    eidx[p] = e;
    srcp[p] = src[e];
    dstp[p] = d;
  }
}

// ---------------------------------------------------------------------------
// xlxr via MFMA (verified R8)
// ---------------------------------------------------------------------------
__global__ __launch_bounds__(256) void xlxr_mfma_kernel(
    const unsigned short* __restrict__ Xb,    // [NN][96]
    const unsigned short* __restrict__ WlTb,  // [576][96]
    const float* __restrict__ bl,
    const unsigned short* __restrict__ WrTb,  // [576][96]
    const float* __restrict__ br,
    unsigned short* __restrict__ xlb, unsigned short* __restrict__ xrb) {
  int t = threadIdx.x;
  int wave = t >> 6, lane = t & 63;
  int l15 = lane & 15, quad = lane >> 4;
  int node = blockIdx.x * 64 + wave * 16 + l15;
  int nclamp = (node < NN) ? node : (NN - 1);
  bool valid = node < NN;
  const unsigned short* brow = &Xb[(size_t)nclamp * 96 + quad * 8];
  bf16x8 b0 = *(const bf16x8*)&brow[0];
  bf16x8 b1 = *(const bf16x8*)&brow[32];
  bf16x8 b2 = *(const bf16x8*)&brow[64];
#pragma unroll
  for (int mt = 0; mt < 36; mt++) {
    int wc = mt * 16 + l15;
    const unsigned short* aL = &WlTb[(size_t)wc * 96 + quad * 8];
    f32x4 accL = {0.f, 0.f, 0.f, 0.f};
    accL = __builtin_amdgcn_mfma_f32_16x16x32_bf16(*(const bf16x8*)&aL[0], b0, accL, 0, 0, 0);
    accL = __builtin_amdgcn_mfma_f32_16x16x32_bf16(*(const bf16x8*)&aL[32], b1, accL, 0, 0, 0);
    accL = __builtin_amdgcn_mfma_f32_16x16x32_bf16(*(const bf16x8*)&aL[64], b2, accL, 0, 0, 0);
    const unsigned short* aR = &WrTb[(size_t)wc * 96 + quad * 8];
    f32x4 accR = {0.f, 0.f, 0.f, 0.f};
    accR = __builtin_amdgcn_mfma_f32_16x16x32_bf16(*(const bf16x8*)&aR[0], b0, accR, 0, 0, 0);
    accR = __builtin_amdgcn_mfma_f32_16x16x32_bf16(*(const bf16x8*)&aR[32], b1, accR, 0, 0, 0);
    accR = __builtin_amdgcn_mfma_f32_16x16x32_bf16(*(const bf16x8*)&aR[64], b2, accR, 0, 0, 0);
    if (valid) {
      int c0 = mt * 16 + quad * 4;
      float4 bbL = *(const float4*)&bl[c0];
      float4 bbR = *(const float4*)&br[c0];
      ushort4 pL, pR;
      pL.x = f2bf(accL[0] + bbL.x); pL.y = f2bf(accL[1] + bbL.y);
      pL.z = f2bf(accL[2] + bbL.z); pL.w = f2bf(accL[3] + bbL.w);
      pR.x = f2bf(accR[0] + bbR.x); pR.y = f2bf(accR[1] + bbR.y);
      pR.z = f2bf(accR[2] + bbR.z); pR.w = f2bf(accR[3] + bbR.w);
      *(ushort4*)&xlb[(size_t)node * 576 + c0] = pL;
      *(ushort4*)&xrb[(size_t)node * 576 + c0] = pR;
    }
  }
}

// ---------------------------------------------------------------------------
// Logits v6 (R10 best): ONE WAVE per block (16 edges), per-head-pair gather
// prefetch before the ee MFMA phase.
// ---------------------------------------------------------------------------
__global__ __launch_bounds__(64) void logits_mfma_kernel(
    const unsigned short* __restrict__ EMBb,   // [NE][96]
    const unsigned short* __restrict__ WeTb,   // [576][96]
    const float* __restrict__ attw,            // [576]
    const unsigned short* __restrict__ XLb,    // [NN][576]
    const unsigned short* __restrict__ XRb,    // [NN][576]
    const int* __restrict__ eidx, const int* __restrict__ srcp,
    const int* __restrict__ dstp,
    float* __restrict__ logp) {               // [NE][6] permuted order
  __shared__ __align__(16) unsigned short eeb[16][200];
  __shared__ int sd[16][2];
  int t = threadIdx.x;
  int p0 = blockIdx.x * 16;
  if (t < 32) sd[t >> 1][t & 1] = (t & 1) ? dstp[p0 + (t >> 1)] : srcp[p0 + (t >> 1)];
  int l15 = t & 15, quad = t >> 4;
  int erow = eidx[p0 + l15];
  const unsigned short* arow = &EMBb[(size_t)erow * 96 + quad * 8];
  bf16x8 a0 = *(const bf16x8*)&arow[0];
  bf16x8 a1 = *(const bf16x8*)&arow[32];
  bf16x8 a2 = *(const bf16x8*)&arow[64];
  __syncthreads();

  int el2 = t >> 2;
  int cq = (t & 3) * 24;
  int gsrc = sd[el2][0];
  int gdst = sd[el2][1];

  for (int hp = 0; hp < 3; hp++) {
    int h0 = hp * 2, h1 = hp * 2 + 1;
    // prefetch gathers for this head-pair
    const unsigned short* xl0 = &XLb[(size_t)gsrc * 576 + h0 * 96 + cq];
    const unsigned short* xr0 = &XRb[(size_t)gdst * 576 + h0 * 96 + cq];
    const unsigned short* xl1 = &XLb[(size_t)gsrc * 576 + h1 * 96 + cq];
    const unsigned short* xr1 = &XRb[(size_t)gdst * 576 + h1 * 96 + cq];
    bf16x8 gl0[3], gr0[3], gl1[3], gr1[3];
#pragma unroll
    for (int c8 = 0; c8 < 3; c8++) {
      gl0[c8] = *(const bf16x8*)&xl0[c8 * 8];
      gr0[c8] = *(const bf16x8*)&xr0[c8 * 8];
      gl1[c8] = *(const bf16x8*)&xl1[c8 * 8];
      gr1[c8] = *(const bf16x8*)&xr1[c8 * 8];
    }
    // ee for heads (h0, h1) via MFMA -> LDS (bf16)
#pragma unroll
    for (int nt = 0; nt < 12; nt++) {
      int col = hp * 192 + nt * 16 + l15;
      const unsigned short* brow = &WeTb[(size_t)col * 96 + quad * 8];
      bf16x8 b0 = *(const bf16x8*)&brow[0];
      bf16x8 b1 = *(const bf16x8*)&brow[32];
      bf16x8 b2 = *(const bf16x8*)&brow[64];
      f32x4 acc = {0.f, 0.f, 0.f, 0.f};
      acc = __builtin_amdgcn_mfma_f32_16x16x32_bf16(a0, b0, acc, 0, 0, 0);
      acc = __builtin_amdgcn_mfma_f32_16x16x32_bf16(a1, b1, acc, 0, 0, 0);
      acc = __builtin_amdgcn_mfma_f32_16x16x32_bf16(a2, b2, acc, 0, 0, 0);
#pragma unroll
      for (int r = 0; r < 4; r++)
        eeb[quad * 4 + r][nt * 16 + l15] = f2bf(acc[r]);
    }
    __syncthreads();
    // combine: leaky + attw dot for both heads
    float pl0 = 0.f, pl1 = 0.f;
    {
      const unsigned short* ee0 = &eeb[el2][cq];
      const unsigned short* ee1 = &eeb[el2][96 + cq];
      const f32x4* ap0 = (const f32x4*)&attw[h0 * 96 + cq];
      const f32x4* ap1 = (const f32x4*)&attw[h1 * 96 + cq];
#pragma unroll
      for (int c8 = 0; c8 < 3; c8++) {
        bf16x8 ev0 = *(const bf16x8*)&ee0[c8 * 8];
        bf16x8 ev1 = *(const bf16x8*)&ee1[c8 * 8];
        f32x4 a00 = ap0[c8 * 2], a01 = ap0[c8 * 2 + 1];
        f32x4 a10 = ap1[c8 * 2], a11 = ap1[c8 * 2 + 1];
#pragma unroll
        for (int j = 0; j < 4; j++) {
          float v0 = bf2f((unsigned short)ev0[j]) +
                     bf2f((unsigned short)gl0[c8][j]) +
                     bf2f((unsigned short)gr0[c8][j]);
          v0 = (v0 > 0.f) ? v0 : 0.2f * v0;
          pl0 += v0 * a00[j];
          float w0 = bf2f((unsigned short)ev0[j + 4]) +
                     bf2f((unsigned short)gl0[c8][j + 4]) +
                     bf2f((unsigned short)gr0[c8][j + 4]);
          w0 = (w0 > 0.f) ? w0 : 0.2f * w0;
          pl0 += w0 * a01[j];
          float v1 = bf2f((unsigned short)ev1[j]) +
                     bf2f((unsigned short)gl1[c8][j]) +
                     bf2f((unsigned short)gr1[c8][j]);
          v1 = (v1 > 0.f) ? v1 : 0.2f * v1;
          pl1 += v1 * a10[j];
          float w1 = bf2f((unsigned short)ev1[j + 4]) +
                     bf2f((unsigned short)gl1[c8][j + 4]) +
                     bf2f((unsigned short)gr1[c8][j + 4]);
          w1 = (w1 > 0.f) ? w1 : 0.2f * w1;
          pl1 += w1 * a11[j];
        }
      }
    }
    pl0 += __shfl_xor(pl0, 1); pl0 += __shfl_xor(pl0, 2);
    pl1 += __shfl_xor(pl1, 1); pl1 += __shfl_xor(pl1, 2);
    if ((t & 3) == 0) {
      size_t base = (size_t)(p0 + el2) * 6 + hp * 2;
      logp[base] = pl0;
      logp[base + 1] = pl1;
    }
    __syncthreads();
  }
}

// ---------------------------------------------------------------------------
// Alpha: wave-per-node segment softmax over dst-sorted logits.
// ---------------------------------------------------------------------------
__global__ __launch_bounds__(256) void alpha_kernel(
    const float* __restrict__ logp, const int* __restrict__ rowptr,
    float* __restrict__ alpha) {
  int node = blockIdx.x * 4 + (threadIdx.x >> 6);
  int lane = threadIdx.x & 63;
  if (node >= NN) return;
  int r0 = rowptr[node], r1 = rowptr[node + 1];
  int d = r1 - r0;
  if (d == 0) return;
  if (d <= 64) {
    bool act = lane < d;
    int p = r0 + (act ? lane : (d - 1));
    float lg[6];
#pragma unroll
    for (int h = 0; h < 6; h++) lg[h] = logp[(size_t)p * 6 + h];
#pragma unroll
    for (int h = 0; h < 6; h++) {
      float m = act ? lg[h] : -1e30f;
#pragma unroll
      for (int off = 32; off > 0; off >>= 1) m = fmaxf(m, __shfl_xor(m, off));
      float w = act ? expf(lg[h] - m) : 0.f;
      float s = w;
#pragma unroll
      for (int off = 32; off > 0; off >>= 1) s += __shfl_xor(s, off);
      if (act) alpha[(size_t)p * 6 + h] = w / (s + 1e-16f);
    }
  } else {
    float m[6], s[6];
#pragma unroll
    for (int h = 0; h < 6; h++) { m[h] = -1e30f; s[h] = 0.f; }
    for (int cs = 0; cs < d; cs += 64) {
      int cnt = min(64, d - cs);
      bool act = lane < cnt;
      int p = r0 + cs + (act ? lane : (cnt - 1));
#pragma unroll
      for (int h = 0; h < 6; h++) {
        float lg = act ? logp[(size_t)p * 6 + h] : -1e30f;
        float cm = lg;
#pragma unroll
        for (int off = 32; off > 0; off >>= 1) cm = fmaxf(cm, __shfl_xor(cm, off));
        float newm = fmaxf(m[h], cm);
        float w = act ? expf(lg - newm) : 0.f;
        float ss = w;
#pragma unroll
        for (int off = 32; off > 0; off >>= 1) ss += __shfl_xor(ss, off);
        s[h] = s[h] * expf(m[h] - newm) + ss;
        m[h] = newm;
      }
    }
    float inv[6];
#pragma unroll
    for (int h = 0; h < 6; h++) inv[h] = 1.f / (s[h] + 1e-16f);
    for (int cs = 0; cs < d; cs += 64) {
      int cnt = min(64, d - cs);
      if (lane < cnt) {
        int p = r0 + cs + lane;
#pragma unroll
        for (int h = 0; h < 6; h++)
          alpha[(size_t)p * 6 + h] =
              expf(logp[(size_t)p * 6 + h] - m[h]) * inv[h];
      }
    }
  }
}

// ---------------------------------------------------------------------------
// Aggregate v4 (R10): barrier-free weighted gather, 4x unroll.
// ---------------------------------------------------------------------------
__global__ __launch_bounds__(576) void aggregate_kernel(
    float* __restrict__ x, unsigned short* __restrict__ xb,
    const unsigned short* __restrict__ XLb,
    const float* __restrict__ alpha, const int* __restrict__ rowptr,
    const int* __restrict__ srcp,
    const float* __restrict__ cbias, const float* __restrict__ lng,
    const float* __restrict__ lnb, int do_elu) {
  int n = blockIdx.x;
  int t = threadIdx.x;
  int r0 = rowptr[n];
  int d = rowptr[n + 1] - r0;
  __shared__ float scratch[576];
  __shared__ float fin[96];
  __shared__ float part[2][2];
  __shared__ float red[2];
  int wave = t >> 6, lane = t & 63;
  int h = t / 96;
  float acc = 0.f;
  int j = 0;
  for (; j + 4 <= d; j += 4) {
    int p = r0 + j;
    float w0 = alpha[(size_t)(p + 0) * 6 + h];
    float w1 = alpha[(size_t)(p + 1) * 6 + h];
    float w2 = alpha[(size_t)(p + 2) * 6 + h];
    float w3 = alpha[(size_t)(p + 3) * 6 + h];
    int s0 = srcp[p + 0], s1 = srcp[p + 1];
    int s2 = srcp[p + 2], s3 = srcp[p + 3];
    float x0 = bf2f(XLb[(size_t)s0 * 576 + t]);
    float x1 = bf2f(XLb[(size_t)s1 * 576 + t]);
    float x2 = bf2f(XLb[(size_t)s2 * 576 + t]);
    float x3 = bf2f(XLb[(size_t)s3 * 576 + t]);
    acc += w0 * x0 + w1 * x1 + w2 * x2 + w3 * x3;
  }
  for (; j < d; j++) {
    int p = r0 + j;
    acc += alpha[(size_t)p * 6 + h] * bf2f(XLb[(size_t)srcp[p] * 576 + t]);
  }
  scratch[t] = acc;
  __syncthreads();
  float fv = 0.f;
  if (t < 96) {
    float s = 0.f;
    for (int hh = 0; hh < 6; hh++) s += scratch[hh * 96 + t];
    s = s * (1.f / 6.f) + cbias[t];
    if (do_elu) s = (s > 0.f) ? s : expm1f(s);
    fv = s;
    fin[t] = s;
  }
  if (wave < 2) {
    float ps = (t < 96) ? fv : 0.f;
    float ps2 = (t < 96) ? fv * fv : 0.f;
#pragma unroll
    for (int off = 32; off > 0; off >>= 1) {
      ps += __shfl_xor(ps, off);
      ps2 += __shfl_xor(ps2, off);
    }
    if (lane == 0) { part[wave][0] = ps; part[wave][1] = ps2; }
  }
  __syncthreads();
  if (t == 0) {
    float s = part[0][0] + part[1][0];
    float s2 = part[0][1] + part[1][1];
    float mu = s / 96.f;
    float var = s2 / 96.f - mu * mu;
    red[0] = mu; red[1] = rsqrtf(var + 1e-5f);
  }
  __syncthreads();
  if (t < 96) {
    float y = (fin[t] - red[0]) * red[1] * lng[t] + lnb[t];
    float nv = x[(size_t)n * 96 + t] + y;
    x[(size_t)n * 96 + t] = nv;
    xb[(size_t)n * 96 + t] = f2bf(nv);
  }
}

// ---------------------------------------------------------------------------
// Predictor via MFMA (verified in R4)
// ---------------------------------------------------------------------------
__global__ __launch_bounds__(256) void pred_mfma_kernel(
    const unsigned short* __restrict__ Xb,     // [NN][96]
    const unsigned short* __restrict__ EMBb,   // [NE][96]
    const int* __restrict__ src, const int* __restrict__ dst,
    const unsigned short* __restrict__ p1wT,   // [128][288]
    const float* __restrict__ p1b, const float* __restrict__ p1g,
    const float* __restrict__ p1be,
    const unsigned short* __restrict__ p2wT,   // [64][128]
    const float* __restrict__ p2b, const float* __restrict__ p2g,
    const float* __restrict__ p2be,
    const float* __restrict__ p3w, const float* __restrict__ p3b,
    float* __restrict__ out) {
  __shared__ unsigned short h1s[4][16][136];
  int t = threadIdx.x;
  int wave = t >> 6, lane = t & 63;
  int l15 = lane & 15, quad = lane >> 4;
  int ebase = blockIdx.x * 64 + wave * 16;
  int erow = ebase + l15;
  int sN = src[erow], dN = dst[erow];

  bf16x8 A[9];
  const unsigned short* xs = &Xb[(size_t)sN * 96 + quad * 8];
  const unsigned short* xd = &Xb[(size_t)dN * 96 + quad * 8];
  const unsigned short* em = &EMBb[(size_t)erow * 96 + quad * 8];
#pragma unroll
  for (int c = 0; c < 3; c++) {
    A[c]     = *(const bf16x8*)&xs[c * 32];
    A[c + 3] = *(const bf16x8*)&xd[c * 32];
    A[c + 6] = *(const bf16x8*)&em[c * 32];
  }

  f32x4 C1[8];
#pragma unroll
  for (int nt = 0; nt < 8; nt++) {
    f32x4 acc = {0.f, 0.f, 0.f, 0.f};
    const unsigned short* bp = &p1wT[(size_t)(nt * 16 + l15) * 288 + quad * 8];
#pragma unroll
    for (int c = 0; c < 9; c++) {
      bf16x8 B = *(const bf16x8*)&bp[c * 32];
      acc = __builtin_amdgcn_mfma_f32_16x16x32_bf16(A[c], B, acc, 0, 0, 0);
    }
    float bias = p1b[nt * 16 + l15];
    acc[0] += bias; acc[1] += bias; acc[2] += bias; acc[3] += bias;
    C1[nt] = acc;
  }

  float mu1[4], rs1[4];
#pragma unroll
  for (int r = 0; r < 4; r++) {
    float s = 0.f, s2 = 0.f;
#pragma unroll
    for (int nt = 0; nt < 8; nt++) { float v = C1[nt][r]; s += v; s2 += v * v; }
    s += __shfl_xor(s, 1);  s += __shfl_xor(s, 2);
    s += __shfl_xor(s, 4);  s += __shfl_xor(s, 8);
    s2 += __shfl_xor(s2, 1); s2 += __shfl_xor(s2, 2);
    s2 += __shfl_xor(s2, 4); s2 += __shfl_xor(s2, 8);
    float mu = s * (1.f / 128.f);
    float var = s2 * (1.f / 128.f) - mu * mu;
    mu1[r] = mu;
    rs1[r] = rsqrtf(var + 1e-5f);
  }
#pragma unroll
  for (int nt = 0; nt < 8; nt++) {
    float g = p1g[nt * 16 + l15], be = p1be[nt * 16 + l15];
#pragma unroll
    for (int r = 0; r < 4; r++) {
      float v = (C1[nt][r] - mu1[r]) * rs1[r] * g + be;
      v = fmaxf(v, 0.f);
      h1s[wave][quad * 4 + r][nt * 16 + l15] = f2bf(v);
    }
  }
  __syncthreads();

  f32x4 C2[4];
#pragma unroll
  for (int nt = 0; nt < 4; nt++) {
    f32x4 acc = {0.f, 0.f, 0.f, 0.f};
    const unsigned short* bp = &p2wT[(size_t)(nt * 16 + l15) * 128 + quad * 8];
#pragma unroll
    for (int c = 0; c < 4; c++) {
      bf16x8 Af = *(const bf16x8*)&h1s[wave][l15][c * 32 + quad * 8];
      bf16x8 B = *(const bf16x8*)&bp[c * 32];
      acc = __builtin_amdgcn_mfma_f32_16x16x32_bf16(Af, B, acc, 0, 0, 0);
    }
    float bias = p2b[nt * 16 + l15];
    acc[0] += bias; acc[1] += bias; acc[2] += bias; acc[3] += bias;
    C2[nt] = acc;
  }

  float mu2[4], rs2[4];
#pragma unroll
  for (int r = 0; r < 4; r++) {
    float s = 0.f, s2 = 0.f;
#pragma unroll
    for (int nt = 0; nt < 4; nt++) { float v = C2[nt][r]; s += v; s2 += v * v; }
    s += __shfl_xor(s, 1);  s += __shfl_xor(s, 2);
    s += __shfl_xor(s, 4);  s += __shfl_xor(s, 8);
    s2 += __shfl_xor(s2, 1); s2 += __shfl_xor(s2, 2);
    s2 += __shfl_xor(s2, 4); s2 += __shfl_xor(s2, 8);
    float mu = s * (1.f / 64.f);
    float var = s2 * (1.f / 64.f) - mu * mu;
    mu2[r] = mu;
    rs2[r] = rsqrtf(var + 1e-5f);
  }

  float partial[4] = {0.f, 0.f, 0.f, 0.f};
#pragma unroll
  for (int nt = 0; nt < 4; nt++) {
    float g = p2g[nt * 16 + l15], be = p2be[nt * 16 + l15];
    float pw = p3w[nt * 16 + l15];
#pragma unroll
    for (int r = 0; r < 4; r++) {
      float v = (C2[nt][r] - mu2[r]) * rs2[r] * g + be;
      v = fmaxf(v, 0.f);
      partial[r] += v * pw;
    }
  }
#pragma unroll
  for (int r = 0; r < 4; r++) {
    float p = partial[r];
    p += __shfl_xor(p, 1);
    p += __shfl_xor(p, 2);
    p += __shfl_xor(p, 4);
    p += __shfl_xor(p, 8);
    partial[r] = p;
  }
  if (l15 == 0) {
    float b3 = p3b[0];
#pragma unroll
    for (int r = 0; r < 4; r++)
      out[ebase + quad * 4 + r] = partial[r] + b3;
  }
}

// ---------------------------------------------------------------------------
static inline size_t alignup(size_t v) { return (v + 255) & ~(size_t)255; }

extern "C" void kernel_launch(void* const* d_in, const int* in_sizes, int n_in,
                              void* d_out, int out_size, void* d_ws, size_t ws_size,
                              hipStream_t stream) {
  const float* x_in      = (const float*)d_in[0];
  const float* edge_attr = (const float*)d_in[1];
  const int*   ei        = (const int*)d_in[2];
  const int* src = ei;
  const int* dst = ei + NE;
  const float* ne_w = (const float*)d_in[3];
  const float* ne_b = (const float*)d_in[4];
  const float* ne_g = (const float*)d_in[5];
  const float* ne_be = (const float*)d_in[6];
  const float* ee_w = (const float*)d_in[7];
  const float* ee_b = (const float*)d_in[8];
  const float* ee_g = (const float*)d_in[9];
  const float* ee_be = (const float*)d_in[10];
  const float* Wl = (const float*)d_in[11];
  const float* bl = (const float*)d_in[12];
  const float* Wr = (const float*)d_in[13];
  const float* br = (const float*)d_in[14];
  const float* We = (const float*)d_in[15];
  const float* attw = (const float*)d_in[16];
  const float* cbias = (const float*)d_in[17];
  const float* lng = (const float*)d_in[18];
  const float* lnb = (const float*)d_in[19];
  const float* p1w = (const float*)d_in[20];
  const float* p1b = (const float*)d_in[21];
  const float* p1g = (const float*)d_in[22];
  const float* p1be = (const float*)d_in[23];
  const float* p2w = (const float*)d_in[24];
  const float* p2b = (const float*)d_in[25];
  const float* p2g = (const float*)d_in[26];
  const float* p2be = (const float*)d_in[27];
  const float* p3w = (const float*)d_in[28];
  const float* p3b = (const float*)d_in[29];
  float* out = (float*)d_out;

  // workspace carve (aligned)
  char* w = (char*)d_ws;
  float* X    = (float*)w; w += alignup((size_t)NN * 96 * 4);
  float* LOG  = (float*)w; w += alignup((size_t)NE * 6 * 4);
  float* ALPHA = (float*)w; w += alignup((size_t)NE * 6 * 4);
  unsigned short* EMBb = (unsigned short*)w; w += alignup((size_t)NE * 96 * 2);
  unsigned short* XLb  = (unsigned short*)w; w += alignup((size_t)NN * 576 * 2);
  unsigned short* XRb  = (unsigned short*)w; w += alignup((size_t)NN * 576 * 2);
  unsigned short* Xb   = (unsigned short*)w; w += alignup((size_t)NN * 96 * 2);
  unsigned short* WeTb = (unsigned short*)w; w += alignup((size_t)3 * 576 * 96 * 2);
  unsigned short* WlTb = (unsigned short*)w; w += alignup((size_t)3 * 576 * 96 * 2);
  unsigned short* WrTb = (unsigned short*)w; w += alignup((size_t)3 * 576 * 96 * 2);
  unsigned short* p1wT = (unsigned short*)w; w += alignup((size_t)128 * 288 * 2);
  unsigned short* p2wT = (unsigned short*)w; w += alignup((size_t)64 * 128 * 2);
  int* deg    = (int*)w; w += alignup((size_t)(NN + 1) * 4);
  int* rowptr = (int*)w; w += alignup((size_t)(NN + 1) * 4);
  int* cursor = (int*)w; w += alignup((size_t)NN * 4);
  int* eidx   = (int*)w; w += alignup((size_t)NE * 4);
  int* srcp   = (int*)w; w += alignup((size_t)NE * 4);
  int* dstp   = (int*)w; w += alignup((size_t)NE * 4);

  // encoders + weight prep
  encode4_kernel<<<NN / 4, 512, 0, stream>>>(x_in, 4, ne_w, ne_b, ne_g, ne_be, X, Xb);
  encode4_kernel<<<NE / 4, 512, 0, stream>>>(edge_attr, 3, ee_w, ee_b, ee_g, ee_be,
                                             nullptr, EMBb);
  convW_kernel<<<(3 * 576 * 96 + 255) / 256, 256, 0, stream>>>(
      We, WeTb, Wl, WlTb, Wr, WrTb, p1w, p1wT, p2w, p2wT);

  // CSR by dst
  hipMemsetAsync(deg, 0, (size_t)(NN + 1) * 4, stream);
  hist_kernel<<<(NE + 255) / 256, 256, 0, stream>>>(dst, deg);
  scan_kernel<<<1, 1024, 0, stream>>>(deg, rowptr, cursor);
  scatter_kernel<<<(NE + 255) / 256, 256, 0, stream>>>(src, dst, cursor, eidx,
                                                       srcp, dstp);

  // 3 GATv2 layers
  for (int i = 0; i < 3; i++) {
    const unsigned short* WlT_i = WlTb + (size_t)i * 576 * 96;
    const float* bl_i = bl + (size_t)i * 576;
    const unsigned short* WrT_i = WrTb + (size_t)i * 576 * 96;
    const float* br_i = br + (size_t)i * 576;
    const unsigned short* WeT_i = WeTb + (size_t)i * 576 * 96;
    const float* aw_i = attw + (size_t)i * 576;
    const float* cb_i = cbias + (size_t)i * 96;
    const float* lg_i = lng + (size_t)i * 96;
    const float* lb_i = lnb + (size_t)i * 96;
    xlxr_mfma_kernel<<<(NN + 63) / 64, 256, 0, stream>>>(Xb, WlT_i, bl_i,
                                                         WrT_i, br_i, XLb, XRb);
    logits_mfma_kernel<<<NE / 16, 64, 0, stream>>>(EMBb, WeT_i, aw_i, XLb, XRb,
                                                   eidx, srcp, dstp, LOG);
    alpha_kernel<<<(NN + 3) / 4, 256, 0, stream>>>(LOG, rowptr, ALPHA);
    aggregate_kernel<<<NN, 576, 0, stream>>>(X, Xb, XLb, ALPHA, rowptr, srcp,
                                             cb_i, lg_i, lb_i, (i < 2) ? 1 : 0);
  }

  // predictor (MFMA)
  pred_mfma_kernel<<<NE / 64, 256, 0, stream>>>(Xb, EMBb, src, dst,
                                                p1wT, p1b, p1g, p1be,
                                                p2wT, p2b, p2g, p2be,
                                                p3w, p3b, out);
}